// Round 7
// baseline (303.529 us; speedup 1.0000x reference)
//
#include <hip/hip_runtime.h>

// VectorQuantizer: z (8,64,8192) f32, codebook (1024,64) f32
// Outputs (concatenated f32): z_q_st [4194304], vq_loss [1], codes [65536]
//
// codes must match numpy fp32 argmin BIT-EXACTLY -> replicate numpy op order:
//   zsq/wsq: pairwise_sum n=64 (8 serial column accumulators, rounded squares)
//   dot:     single serial FMA chain over k ascending (BLAS sgemm order)
//   dist:    fl(fl(zsq - fl(2*dot)) + wsq), argmin = first occurrence of min.
//
// R3-R6 lesson: any design needing 64 per-lane z values in VGPRs loses to the
// allocator's occupancy heuristic (scratch demotion / load sinking / spills /
// crash). THIS design needs ~30 VGPRs: z lives in LDS (stride 65 -> 2-way
// bank aliasing, free), codebook streams via wave-uniform s_loads, 8 serial
// FMA chains in flight. LICM of the loop-invariant ds_reads is blocked by an
// opaque asm SGPR offset regenerated per code-iteration.

#define T_DIM 8192
#define D_DIM 64
#define C_DIM 1024
#define B_DIM 8
#define NROWS (B_DIM * T_DIM)           // 65536 vectors
#define NELEM (B_DIM * D_DIM * T_DIM)   // 4194304 elements
#define SEGS 4
#define CODES_PER_SEG (C_DIM / SEGS)    // 256
#define BLK 128                          // threads per dist block
#define ZSTRIDE 65                       // LDS row stride: (65*i+k)%32 -> 2-way
#define EPI_BLOCKS (NELEM / 4 / 256)    // 4096 blocks, 1 float4/thread

#define R64(M) M(0) M(1) M(2) M(3) M(4) M(5) M(6) M(7) \
  M(8) M(9) M(10) M(11) M(12) M(13) M(14) M(15) \
  M(16) M(17) M(18) M(19) M(20) M(21) M(22) M(23) \
  M(24) M(25) M(26) M(27) M(28) M(29) M(30) M(31) \
  M(32) M(33) M(34) M(35) M(36) M(37) M(38) M(39) \
  M(40) M(41) M(42) M(43) M(44) M(45) M(46) M(47) \
  M(48) M(49) M(50) M(51) M(52) M(53) M(54) M(55) \
  M(56) M(57) M(58) M(59) M(60) M(61) M(62) M(63)

#define SQ_(x) __fmul_rn(x, x)
#define AD_(a, b) __fadd_rn(a, b)

// numpy pairwise_sum of 64 pre-rounded squares of scalars p0..p63 -> dst.
#define PAIRWISE64(p, dst) \
  float pr0 = SQ_(p##0);  pr0 = AD_(pr0, SQ_(p##8));  pr0 = AD_(pr0, SQ_(p##16)); pr0 = AD_(pr0, SQ_(p##24)); pr0 = AD_(pr0, SQ_(p##32)); pr0 = AD_(pr0, SQ_(p##40)); pr0 = AD_(pr0, SQ_(p##48)); pr0 = AD_(pr0, SQ_(p##56)); \
  float pr1 = SQ_(p##1);  pr1 = AD_(pr1, SQ_(p##9));  pr1 = AD_(pr1, SQ_(p##17)); pr1 = AD_(pr1, SQ_(p##25)); pr1 = AD_(pr1, SQ_(p##33)); pr1 = AD_(pr1, SQ_(p##41)); pr1 = AD_(pr1, SQ_(p##49)); pr1 = AD_(pr1, SQ_(p##57)); \
  float pr2 = SQ_(p##2);  pr2 = AD_(pr2, SQ_(p##10)); pr2 = AD_(pr2, SQ_(p##18)); pr2 = AD_(pr2, SQ_(p##26)); pr2 = AD_(pr2, SQ_(p##34)); pr2 = AD_(pr2, SQ_(p##42)); pr2 = AD_(pr2, SQ_(p##50)); pr2 = AD_(pr2, SQ_(p##58)); \
  float pr3 = SQ_(p##3);  pr3 = AD_(pr3, SQ_(p##11)); pr3 = AD_(pr3, SQ_(p##19)); pr3 = AD_(pr3, SQ_(p##27)); pr3 = AD_(pr3, SQ_(p##35)); pr3 = AD_(pr3, SQ_(p##43)); pr3 = AD_(pr3, SQ_(p##51)); pr3 = AD_(pr3, SQ_(p##59)); \
  float pr4 = SQ_(p##4);  pr4 = AD_(pr4, SQ_(p##12)); pr4 = AD_(pr4, SQ_(p##20)); pr4 = AD_(pr4, SQ_(p##28)); pr4 = AD_(pr4, SQ_(p##36)); pr4 = AD_(pr4, SQ_(p##44)); pr4 = AD_(pr4, SQ_(p##52)); pr4 = AD_(pr4, SQ_(p##60)); \
  float pr5 = SQ_(p##5);  pr5 = AD_(pr5, SQ_(p##13)); pr5 = AD_(pr5, SQ_(p##21)); pr5 = AD_(pr5, SQ_(p##29)); pr5 = AD_(pr5, SQ_(p##37)); pr5 = AD_(pr5, SQ_(p##45)); pr5 = AD_(pr5, SQ_(p##53)); pr5 = AD_(pr5, SQ_(p##61)); \
  float pr6 = SQ_(p##6);  pr6 = AD_(pr6, SQ_(p##14)); pr6 = AD_(pr6, SQ_(p##22)); pr6 = AD_(pr6, SQ_(p##30)); pr6 = AD_(pr6, SQ_(p##38)); pr6 = AD_(pr6, SQ_(p##46)); pr6 = AD_(pr6, SQ_(p##54)); pr6 = AD_(pr6, SQ_(p##62)); \
  float pr7 = SQ_(p##7);  pr7 = AD_(pr7, SQ_(p##15)); pr7 = AD_(pr7, SQ_(p##23)); pr7 = AD_(pr7, SQ_(p##31)); pr7 = AD_(pr7, SQ_(p##39)); pr7 = AD_(pr7, SQ_(p##47)); pr7 = AD_(pr7, SQ_(p##55)); pr7 = AD_(pr7, SQ_(p##63)); \
  float dst = AD_(AD_(AD_(pr0, pr1), AD_(pr2, pr3)), AD_(AD_(pr4, pr5), AD_(pr6, pr7)));

__global__ __launch_bounds__(BLK)
void vq_dist_kernel(const float* __restrict__ z,
                    const float* __restrict__ cb,
                    float2* __restrict__ pairs) {
    __shared__ float z_lds[BLK * ZSTRIDE];   // ~33 KB
    __shared__ float wsqs[CODES_PER_SEG];

    const int tid = threadIdx.x;
    const int row = blockIdx.x * BLK + tid;           // 0..65535
    const int seg = blockIdx.y;                       // 0..3 (uniform)
    const int c0 = seg * CODES_PER_SEG;
    const int b = row >> 13;                          // row / 8192
    const int t = row & (T_DIM - 1);

    // --- ||w||^2 for this segment's 256 codes (numpy op order) ---
    for (int cc = tid; cc < CODES_PER_SEG; cc += BLK) {
        const float* wp = cb + ((size_t)(c0 + cc) << 6);
#define LOADW(k) float w##k = wp[k];
        R64(LOADW)
#undef LOADW
        PAIRWISE64(w, s)
        wsqs[cc] = s;
    }

    // --- stage this thread's z row into LDS; zsq in numpy pairwise order ---
    // z[b, d, t]: stride T_DIM along d; lanes t-consecutive -> coalesced
    const float* zp = z + (size_t)b * (D_DIM * T_DIM) + t;
    float col[8];
#pragma unroll
    for (int d = 0; d < 8; ++d) {
        float v = zp[(size_t)d * T_DIM];
        z_lds[tid * ZSTRIDE + d] = v;
        col[d] = __fmul_rn(v, v);
    }
#pragma unroll
    for (int d = 8; d < 64; ++d) {
        float v = zp[(size_t)d * T_DIM];
        z_lds[tid * ZSTRIDE + d] = v;
        col[d & 7] = __fadd_rn(col[d & 7], __fmul_rn(v, v));
    }
    const float zsq = __fadd_rn(
        __fadd_rn(__fadd_rn(col[0], col[1]), __fadd_rn(col[2], col[3])),
        __fadd_rn(__fadd_rn(col[4], col[5]), __fadd_rn(col[6], col[7])));
    __syncthreads();

    // --- 256 codes, 8 serial FMA chains in flight ---
    const float* zbase = z_lds + tid * ZSTRIDE;
    float bestd = 3.4e38f;
    int besti = 0;
#pragma unroll 1
    for (int cc = 0; cc < CODES_PER_SEG; cc += 8) {
        // Opaque zero offset: defeats LICM of the 64 loop-invariant ds_reads
        // (hoisting them would recreate 64 live VGPRs -> spills, the R3-R6
        // failure mode). asm volatile can't be hoisted or folded.
        int zoff;
        asm volatile("s_mov_b32 %0, 0" : "=s"(zoff));
        const float* zl = zbase + zoff;

        const float* w0p = cb + ((size_t)(c0 + cc) << 6);  // uniform -> s_load
        const float* w1p = w0p + 64;
        const float* w2p = w0p + 128;
        const float* w3p = w0p + 192;
        const float* w4p = w0p + 256;
        const float* w5p = w0p + 320;
        const float* w6p = w0p + 384;
        const float* w7p = w0p + 448;
        float a0 = 0.f, a1 = 0.f, a2 = 0.f, a3 = 0.f;
        float a4 = 0.f, a5 = 0.f, a6 = 0.f, a7 = 0.f;
        // Serial chain over k ascending (sgemm order), one ds_read feeds 8.
#define STEP(k) { float zv = zl[k]; \
        a0 = fmaf(zv, w0p[k], a0); a1 = fmaf(zv, w1p[k], a1); \
        a2 = fmaf(zv, w2p[k], a2); a3 = fmaf(zv, w3p[k], a3); \
        a4 = fmaf(zv, w4p[k], a4); a5 = fmaf(zv, w5p[k], a5); \
        a6 = fmaf(zv, w6p[k], a6); a7 = fmaf(zv, w7p[k], a7); }
        R64(STEP)
#undef STEP
        // d = (zsq - 2*dot) + wsq, each op individually rounded; ascending
        // order + strict < => numpy first-min semantics.
        float d0 = __fadd_rn(__fsub_rn(zsq, __fmul_rn(2.0f, a0)), wsqs[cc + 0]);
        float d1 = __fadd_rn(__fsub_rn(zsq, __fmul_rn(2.0f, a1)), wsqs[cc + 1]);
        float d2 = __fadd_rn(__fsub_rn(zsq, __fmul_rn(2.0f, a2)), wsqs[cc + 2]);
        float d3 = __fadd_rn(__fsub_rn(zsq, __fmul_rn(2.0f, a3)), wsqs[cc + 3]);
        float d4 = __fadd_rn(__fsub_rn(zsq, __fmul_rn(2.0f, a4)), wsqs[cc + 4]);
        float d5 = __fadd_rn(__fsub_rn(zsq, __fmul_rn(2.0f, a5)), wsqs[cc + 5]);
        float d6 = __fadd_rn(__fsub_rn(zsq, __fmul_rn(2.0f, a6)), wsqs[cc + 6]);
        float d7 = __fadd_rn(__fsub_rn(zsq, __fmul_rn(2.0f, a7)), wsqs[cc + 7]);
        if (d0 < bestd) { bestd = d0; besti = c0 + cc + 0; }
        if (d1 < bestd) { bestd = d1; besti = c0 + cc + 1; }
        if (d2 < bestd) { bestd = d2; besti = c0 + cc + 2; }
        if (d3 < bestd) { bestd = d3; besti = c0 + cc + 3; }
        if (d4 < bestd) { bestd = d4; besti = c0 + cc + 4; }
        if (d5 < bestd) { bestd = d5; besti = c0 + cc + 5; }
        if (d6 < bestd) { bestd = d6; besti = c0 + cc + 6; }
        if (d7 < bestd) { bestd = d7; besti = c0 + cc + 7; }
    }
    pairs[seg * NROWS + row] = make_float2(bestd, (float)besti);
}

__global__ void vq_argmin_kernel(const float2* __restrict__ pairs,
                                 float* __restrict__ codes) {
    int row = blockIdx.x * blockDim.x + threadIdx.x;
    float2 best = pairs[row];
#pragma unroll
    for (int s = 1; s < SEGS; ++s) {
        float2 p = pairs[s * NROWS + row];
        if (p.x < best.x) best = p;  // ascending seg order, strict <
    }
    codes[row] = best.y;
}

// One float4 (4 consecutive t) per thread; per-block double partial to ws.
__global__ void vq_epilogue_kernel(const float* __restrict__ z,
                                   const float* __restrict__ cb,
                                   const float* __restrict__ codes,
                                   float* __restrict__ out,
                                   double* __restrict__ partials) {
    const int q = blockIdx.x * 256 + threadIdx.x;  // quad index, 0..1048575
    const int i = q << 2;                          // element index
    const int t = i & (T_DIM - 1);                 // multiple of 4
    const int bd = i >> 13;
    const int d = bd & (D_DIM - 1);                // uniform within a wave
    const int b = bd >> 6;
    const int row = (b << 13) | t;

    float4 cr = *(const float4*)(codes + row);     // 4 consecutive codes
    float4 zv = *(const float4*)(z + i);
    float w0 = cb[((int)cr.x << 6) + d];           // gathers, 256 KiB table
    float w1 = cb[((int)cr.y << 6) + d];
    float w2 = cb[((int)cr.z << 6) + d];
    float w3 = cb[((int)cr.w << 6) + d];

    float4 df = make_float4(w0 - zv.x, w1 - zv.y, w2 - zv.z, w3 - zv.w);
    float4 o = make_float4(zv.x + df.x, zv.y + df.y, zv.z + df.z, zv.w + df.w);
    *(float4*)(out + i) = o;                       // z + (z_q - z), ref order

    double v = (double)df.x * df.x + (double)df.y * df.y +
               (double)df.z * df.z + (double)df.w * df.w;
#pragma unroll
    for (int o2 = 32; o2 > 0; o2 >>= 1) v += __shfl_down(v, o2, 64);

    __shared__ double red[4];
    if ((threadIdx.x & 63) == 0) red[threadIdx.x >> 6] = v;
    __syncthreads();
    if (threadIdx.x == 0)
        partials[blockIdx.x] = ((red[0] + red[1]) + (red[2] + red[3]));
}

__global__ void vq_loss_kernel(const double* __restrict__ partials,
                               float* __restrict__ out_loss) {
    double s = 0.0;
    for (int i = threadIdx.x; i < EPI_BLOCKS; i += 256) s += partials[i];
#pragma unroll
    for (int o = 32; o > 0; o >>= 1) s += __shfl_down(s, o, 64);
    __shared__ double red[4];
    if ((threadIdx.x & 63) == 0) red[threadIdx.x >> 6] = s;
    __syncthreads();
    if (threadIdx.x == 0) {
        double tot = (red[0] + red[1]) + (red[2] + red[3]);
        // vq_loss = codebook_loss + 0.25*commitment_loss = 1.25*mean(diff^2)
        out_loss[0] = (float)(1.25 * tot / (double)NELEM);
    }
}

extern "C" void kernel_launch(void* const* d_in, const int* in_sizes, int n_in,
                              void* d_out, int out_size, void* d_ws, size_t ws_size,
                              hipStream_t stream) {
    const float* z  = (const float*)d_in[0];   // 4194304
    const float* cb = (const float*)d_in[1];   // 65536

    float* out      = (float*)d_out;
    float* out_loss = out + NELEM;             // index 4194304
    float* codes    = out + NELEM + 1;         // 65536 floats

    char* ws    = (char*)d_ws;
    double* partials = (double*)(ws);                  // 32 KiB (4096 doubles)
    float2* pairs = (float2*)(ws + 32768);             // 2 MiB

    dim3 grid1(NROWS / BLK, SEGS);
    vq_dist_kernel<<<grid1, BLK, 0, stream>>>(z, cb, pairs);

    vq_argmin_kernel<<<NROWS / 256, 256, 0, stream>>>(pairs, codes);

    vq_epilogue_kernel<<<EPI_BLOCKS, 256, 0, stream>>>(z, cb, codes, out, partials);

    vq_loss_kernel<<<1, 256, 0, stream>>>(partials, out_loss);
}